// Round 4
// baseline (792.275 us; speedup 1.0000x reference)
//
#include <hip/hip_runtime.h>

typedef unsigned short u16;
typedef __attribute__((ext_vector_type(8))) short bf16x8;
typedef __attribute__((ext_vector_type(4))) float f32x4;

#define C_    192
#define HW_   65536
#define NWIN  4096

__device__ inline u16 f2bf(float f) {
  union { float f; unsigned u; } x; x.f = f;
  unsigned r = x.u + 0x7FFFu + ((x.u >> 16) & 1u);
  return (u16)(r >> 16);
}
__device__ inline float bf2f(u16 s) {
  union { unsigned u; float f; } x; x.u = ((unsigned)s) << 16;
  return x.f;
}

// ---------------- k0: weights fp32 -> bf16, combined qkv bias ----------------
__global__ void k_convert(const float* __restrict__ qkv_w, const float* __restrict__ proj_w,
                          const float* __restrict__ q_bias, const float* __restrict__ v_bias,
                          u16* __restrict__ wq, u16* __restrict__ wp, float* __restrict__ qkvb) {
  int i = blockIdx.x * 256 + threadIdx.x;
  if (i < 110592) wq[i] = f2bf(qkv_w[i]);
  else if (i < 147456) wp[i - 110592] = f2bf(proj_w[i - 110592]);
  else if (i < 148032) {
    int j = i - 147456;
    qkvb[j] = (j < 192) ? q_bias[j] : ((j < 384) ? 0.f : v_bias[j - 384]);
  }
}

// ---------------- k1: CPB MLP table (225 x 8) ----------------
__global__ void k_table(const float* __restrict__ w1, const float* __restrict__ b1,
                        const float* __restrict__ w2, float* __restrict__ table) {
  int row = blockIdx.x;            // 0..224
  int tid = threadIdx.x;
  int a = row / 15, b = row % 15;
  float va = (float)(a - 7) * (8.0f / 7.0f);
  float vb = (float)(b - 7) * (8.0f / 7.0f);
  float c0 = copysignf(log2f(fabsf(va) + 1.0f) * (1.0f / 3.0f), va);
  float c1 = copysignf(log2f(fabsf(vb) + 1.0f) * (1.0f / 3.0f), vb);
  float acc[8];
#pragma unroll
  for (int o = 0; o < 8; ++o) acc[o] = 0.f;
  for (int k = tid; k < 512; k += 256) {
    float h = fmaxf(c0 * w1[k] + c1 * w1[512 + k] + b1[k], 0.f);
#pragma unroll
    for (int o = 0; o < 8; ++o) acc[o] += h * w2[k * 8 + o];
  }
  __shared__ float part[4][8];
  int wave = tid >> 6;
#pragma unroll
  for (int o = 0; o < 8; ++o) {
    float v = acc[o];
    v += __shfl_xor(v, 1, 64);  v += __shfl_xor(v, 2, 64);
    v += __shfl_xor(v, 4, 64);  v += __shfl_xor(v, 8, 64);
    v += __shfl_xor(v, 16, 64); v += __shfl_xor(v, 32, 64);
    acc[o] = v;
  }
  if ((tid & 63) == 0)
#pragma unroll
    for (int o = 0; o < 8; ++o) part[wave][o] = acc[o];
  __syncthreads();
  if (tid < 8)
    table[row * 8 + tid] = part[0][tid] + part[1][tid] + part[2][tid] + part[3][tid];
}

// ---- k2: bias grid permuted for S^T layout: flat = h*4096 + t*64 + g*16 + nt*4 + r
//      (t = query token; s = nt*16 + g*4 + r = key token) ----
__global__ void k_biasfill(const float* __restrict__ table, float* __restrict__ bias3) {
  int p = blockIdx.x * 256 + threadIdx.x;   // 32768 total
  int h = p >> 12, t = (p >> 6) & 63, g = (p >> 4) & 3, u = p & 15;
  int nt = u >> 2, r = u & 3;
  int s = nt * 16 + g * 4 + r;
  int idx = ((t >> 3) - (s >> 3) + 7) * 15 + ((t & 7) - (s & 7) + 7);
  float v = table[idx * 8 + h];
  bias3[p] = 16.0f / (1.0f + __expf(-v));
}

// ---------------- main fused kernel: 1 window/block, 8 waves, 2 blocks/CU ----------------
__global__ __launch_bounds__(512, 4)
void k_main(const float* __restrict__ x,
            const float* __restrict__ ls, const float* __restrict__ proj_b,
            const u16* __restrict__ wq, const u16* __restrict__ wp,
            const float* __restrict__ qkvb, const float* __restrict__ bias3,
            float* __restrict__ out) {
  __shared__ u16 smem[37888];                 // 75,776 B -> 2 blocks/CU
  u16* R0 = smem;                             // [64][200]: x, later ao
  u16* R1 = smem + 12800;                     // q/k [64][200]; v^T [192][72]; obuf bf16 [192][68]
  u16* Pl = smem + 26624;                     // 8 x [16][72] per-wave P bounce ([t][s])
  float* invq = (float*)(smem + 35840);       // [8][64] (logit scale folded)
  float* invk = invq + 512;                   // [8][64]

  int tid  = threadIdx.x;
  int wave = tid >> 6, lane = tid & 63, g = lane >> 4, li = lane & 15;
  int tt = wave & 3, half = wave >> 2;
  int bid = blockIdx.x;
  int b = bid >> 10, wy = (bid >> 5) & 31, wx = bid & 31;
  const float* xb = x + (size_t)b * C_ * HW_;
  int base = (wy * 8) * 256 + wx * 8;
  bf16x8 z8 = {0, 0, 0, 0, 0, 0, 0, 0};
  f32x4 zf = {0.f, 0.f, 0.f, 0.f};

  // ---- P1: stage x -> bf16 LDS [t][c] ----
#pragma unroll
  for (int it = 0; it < 6; ++it) {
    int i4 = tid + it * 512;                  // 3072 tasks
    int c = i4 >> 4, rem = i4 & 15;
    int ty = rem >> 1, jj = (rem & 1) * 4;
    float4 v = *(const float4*)(xb + c * HW_ + base + ty * 256 + jj);
    int t = ty * 8 + jj;
    R0[(t + 0) * 200 + c] = f2bf(v.x);
    R0[(t + 1) * 200 + c] = f2bf(v.y);
    R0[(t + 2) * 200 + c] = f2bf(v.z);
    R0[(t + 3) * 200 + c] = f2bf(v.w);
  }
  __syncthreads();                            // B1

  // X fragments (rows tt*16+li) -- shared by q,k (as B) and v (as A) passes
  bf16x8 xf[6];
#pragma unroll
  for (int ks = 0; ks < 6; ++ks)
    xf[ks] = *(const bf16x8*)&R0[(tt * 16 + li) * 200 + ks * 32 + g * 8];

  // ---- P2a: q GEMM as Y^T = Wq . X^T (C rows = out-channel -> b64 stores) ----
#pragma unroll
  for (int it = 0; it < 6; ++it) {
    int jt = half * 96 + it * 16;
    const u16* wr = wq + (jt + li) * 192 + g * 8;
    f32x4 a0 = zf, a1 = zf;
#pragma unroll
    for (int ks = 0; ks < 3; ++ks) {
      bf16x8 w0 = *(const bf16x8*)(wr + ks * 32);
      bf16x8 w1 = *(const bf16x8*)(wr + (ks + 3) * 32);
      a0 = __builtin_amdgcn_mfma_f32_16x16x32_bf16(w0, xf[ks], a0, 0, 0, 0);
      a1 = __builtin_amdgcn_mfma_f32_16x16x32_bf16(w1, xf[ks + 3], a1, 0, 0, 0);
    }
    f32x4 cb = *(const f32x4*)(qkvb + jt + g * 4);
    uint2 pk;
    pk.x = f2bf(a0[0] + a1[0] + cb[0]) | ((unsigned)f2bf(a0[1] + a1[1] + cb[1]) << 16);
    pk.y = f2bf(a0[2] + a1[2] + cb[2]) | ((unsigned)f2bf(a0[3] + a1[3] + cb[3]) << 16);
    *(uint2*)&R1[(tt * 16 + li) * 200 + jt + g * 4] = pk;
  }
  __syncthreads();                            // B2

  bf16x8 qf[4], kf[4];
  // ---- P3a: invq (+scale) & hoist q B-frags; wave = head ----
  {
    const bf16x8* r8 = (const bf16x8*)&R1[lane * 200 + wave * 24];
    float ssq = 0.f;
#pragma unroll
    for (int ch = 0; ch < 3; ++ch) {
      bf16x8 v8 = r8[ch];
#pragma unroll
      for (int e = 0; e < 8; ++e) { float v = bf2f((u16)v8[e]); ssq += v * v; }
    }
    float inv = __builtin_amdgcn_rsqf(fmaxf(ssq, 1e-24f));
    inv *= __expf(fminf(ls[wave], 4.6051702f));
    invq[wave * 64 + lane] = inv;
#pragma unroll
    for (int tb = 0; tb < 4; ++tb)
      qf[tb] = (g < 3) ? *(const bf16x8*)&R1[(tb * 16 + li) * 200 + wave * 24 + g * 8] : z8;
  }
  __syncthreads();                            // B3

  // ---- P2b: k GEMM (same orientation as q) ----
#pragma unroll
  for (int it = 0; it < 6; ++it) {
    int jt = half * 96 + it * 16;
    const u16* wr = wq + (192 + jt + li) * 192 + g * 8;
    f32x4 a0 = zf, a1 = zf;
#pragma unroll
    for (int ks = 0; ks < 3; ++ks) {
      bf16x8 w0 = *(const bf16x8*)(wr + ks * 32);
      bf16x8 w1 = *(const bf16x8*)(wr + (ks + 3) * 32);
      a0 = __builtin_amdgcn_mfma_f32_16x16x32_bf16(w0, xf[ks], a0, 0, 0, 0);
      a1 = __builtin_amdgcn_mfma_f32_16x16x32_bf16(w1, xf[ks + 3], a1, 0, 0, 0);
    }
    f32x4 cb = *(const f32x4*)(qkvb + 192 + jt + g * 4);
    uint2 pk;
    pk.x = f2bf(a0[0] + a1[0] + cb[0]) | ((unsigned)f2bf(a0[1] + a1[1] + cb[1]) << 16);
    pk.y = f2bf(a0[2] + a1[2] + cb[2]) | ((unsigned)f2bf(a0[3] + a1[3] + cb[3]) << 16);
    *(uint2*)&R1[(tt * 16 + li) * 200 + jt + g * 4] = pk;
  }
  __syncthreads();                            // B4

  // ---- P3b: invk & hoist k A-frags ----
  {
    const bf16x8* r8 = (const bf16x8*)&R1[lane * 200 + wave * 24];
    float ssq = 0.f;
#pragma unroll
    for (int ch = 0; ch < 3; ++ch) {
      bf16x8 v8 = r8[ch];
#pragma unroll
      for (int e = 0; e < 8; ++e) { float v = bf2f((u16)v8[e]); ssq += v * v; }
    }
    invk[wave * 64 + lane] = __builtin_amdgcn_rsqf(fmaxf(ssq, 1e-24f));
#pragma unroll
    for (int nt = 0; nt < 4; ++nt)
      kf[nt] = (g < 3) ? *(const bf16x8*)&R1[(nt * 16 + li) * 200 + wave * 24 + g * 8] : z8;
  }
  __syncthreads();                            // B5

  // ---- P2c: v GEMM (old orientation, C rows = t) -> v^T [192][72] b64 stores ----
#pragma unroll
  for (int it = 0; it < 6; ++it) {
    int jv = half * 96 + it * 16;
    const u16* wr = wq + (384 + jv + li) * 192 + g * 8;
    f32x4 a0 = zf, a1 = zf;
#pragma unroll
    for (int ks = 0; ks < 3; ++ks) {
      bf16x8 w0 = *(const bf16x8*)(wr + ks * 32);
      bf16x8 w1 = *(const bf16x8*)(wr + (ks + 3) * 32);
      a0 = __builtin_amdgcn_mfma_f32_16x16x32_bf16(xf[ks], w0, a0, 0, 0, 0);
      a1 = __builtin_amdgcn_mfma_f32_16x16x32_bf16(xf[ks + 3], w1, a1, 0, 0, 0);
    }
    float cb = qkvb[384 + jv + li];
    uint2 pk;
    pk.x = f2bf(a0[0] + a1[0] + cb) | ((unsigned)f2bf(a0[1] + a1[1] + cb) << 16);
    pk.y = f2bf(a0[2] + a1[2] + cb) | ((unsigned)f2bf(a0[3] + a1[3] + cb) << 16);
    *(uint2*)&R1[(jv + li) * 72 + tt * 16 + g * 4] = pk;
  }
  __syncthreads();                            // B6 (x in R0 dead)

  // ---- P4: attention, S^T = K.Q^T; wave = head; ao -> R0 ----
  {
    int h = wave;
    bf16x8 v0f[2], v1f[2];
#pragma unroll
    for (int ks = 0; ks < 2; ++ks) {
      v0f[ks] = *(const bf16x8*)&R1[(h * 24 + li) * 72 + ks * 32 + g * 8];
      v1f[ks] = (li < 8) ? *(const bf16x8*)&R1[(h * 24 + 16 + li) * 72 + ks * 32 + g * 8] : z8;
    }
    f32x4 ik4[4];
#pragma unroll
    for (int nt = 0; nt < 4; ++nt)
      ik4[nt] = *(const f32x4*)&invk[h * 64 + nt * 16 + g * 4];
    u16* Pw = Pl + wave * 1152;
#pragma unroll
    for (int tb = 0; tb < 4; ++tb) {
      f32x4 s4[4];
#pragma unroll
      for (int nt = 0; nt < 4; ++nt)
        s4[nt] = __builtin_amdgcn_mfma_f32_16x16x32_bf16(kf[nt], qf[tb], zf, 0, 0, 0);
      float iq = invq[h * 64 + tb * 16 + li];
#pragma unroll
      for (int nt = 0; nt < 4; ++nt) {
        f32x4 bx = *(const f32x4*)(bias3 + (((h * 64 + tb * 16 + li) * 4 + g) << 4) + nt * 4);
#pragma unroll
        for (int r = 0; r < 4; ++r)
          s4[nt][r] = s4[nt][r] * iq * ik4[nt][r] + bx[r];
      }
      // softmax over s (16 local values + 2 shfls)
      float m = s4[0][0];
#pragma unroll
      for (int nt = 0; nt < 4; ++nt)
#pragma unroll
        for (int r = 0; r < 4; ++r) m = fmaxf(m, s4[nt][r]);
      m = fmaxf(m, __shfl_xor(m, 16, 64));
      m = fmaxf(m, __shfl_xor(m, 32, 64));
      float sum = 0.f;
#pragma unroll
      for (int nt = 0; nt < 4; ++nt)
#pragma unroll
        for (int r = 0; r < 4; ++r) { float e = __expf(s4[nt][r] - m); s4[nt][r] = e; sum += e; }
      sum += __shfl_xor(sum, 16, 64);
      sum += __shfl_xor(sum, 32, 64);
      float is = __builtin_amdgcn_rcpf(sum);
      // P bounce: [t=li][s] b64 stores (unnormalized exp; 1/sum folded into O)
#pragma unroll
      for (int nt = 0; nt < 4; ++nt) {
        uint2 pk;
        pk.x = f2bf(s4[nt][0]) | ((unsigned)f2bf(s4[nt][1]) << 16);
        pk.y = f2bf(s4[nt][2]) | ((unsigned)f2bf(s4[nt][3]) << 16);
        *(uint2*)&Pw[li * 72 + nt * 16 + g * 4] = pk;
      }
      // PV: O^T = V^T . P^T  (pf = b128 read of P[t=li][s 8-consec])
      f32x4 o0 = zf, o1 = zf;
#pragma unroll
      for (int ks = 0; ks < 2; ++ks) {
        bf16x8 pf = *(const bf16x8*)&Pw[li * 72 + ks * 32 + g * 8];
        o0 = __builtin_amdgcn_mfma_f32_16x16x32_bf16(v0f[ks], pf, o0, 0, 0, 0);
        o1 = __builtin_amdgcn_mfma_f32_16x16x32_bf16(v1f[ks], pf, o1, 0, 0, 0);
      }
      int t = tb * 16 + li;
      {
        uint2 pk;
        pk.x = f2bf(o0[0] * is) | ((unsigned)f2bf(o0[1] * is) << 16);
        pk.y = f2bf(o0[2] * is) | ((unsigned)f2bf(o0[3] * is) << 16);
        *(uint2*)&R0[t * 200 + h * 24 + g * 4] = pk;           // d = g*4..g*4+3
      }
      if (g < 2) {
        uint2 pk;
        pk.x = f2bf(o1[0] * is) | ((unsigned)f2bf(o1[1] * is) << 16);
        pk.y = f2bf(o1[2] * is) | ((unsigned)f2bf(o1[3] * is) << 16);
        *(uint2*)&R0[t * 200 + h * 24 + 16 + g * 4] = pk;      // d = 16+g*4..
      }
    }
  }
  __syncthreads();                            // B7 (v^T/Pl dead)

  // ---- P5: proj as O^T = Wp . ao^T -> obuf bf16 [192][68] in R1 ----
  {
    bf16x8 aof[6];
#pragma unroll
    for (int ks = 0; ks < 6; ++ks)
      aof[ks] = *(const bf16x8*)&R0[(tt * 16 + li) * 200 + ks * 32 + g * 8];
    u16* obuf = R1;
#pragma unroll
    for (int it = 0; it < 6; ++it) {
      int ct = half * 96 + it * 16;
      const u16* wr = wp + (ct + li) * 192 + g * 8;
      f32x4 a0 = zf, a1 = zf;
#pragma unroll
      for (int ks = 0; ks < 3; ++ks) {
        bf16x8 w0 = *(const bf16x8*)(wr + ks * 32);
        bf16x8 w1 = *(const bf16x8*)(wr + (ks + 3) * 32);
        a0 = __builtin_amdgcn_mfma_f32_16x16x32_bf16(w0, aof[ks], a0, 0, 0, 0);
        a1 = __builtin_amdgcn_mfma_f32_16x16x32_bf16(w1, aof[ks + 3], a1, 0, 0, 0);
      }
      f32x4 pb = *(const f32x4*)(proj_b + ct + g * 4);
#pragma unroll
      for (int r = 0; r < 4; ++r)
        obuf[(ct + g * 4 + r) * 68 + tt * 16 + li] = f2bf(a0[r] + a1[r] + pb[r]);
    }
  }
  __syncthreads();                            // B8

  // ---- P6: residual (x re-read) + b64 obuf reads + coalesced store ----
  float* ob = out + (size_t)b * C_ * HW_;
#pragma unroll
  for (int it = 0; it < 6; ++it) {
    int i4 = tid + it * 512;
    int c = i4 >> 4, rem = i4 & 15;
    int ty = rem >> 1, jj = (rem & 1) * 4;
    int t0 = ty * 8 + jj;
    int off = c * HW_ + base + ty * 256 + jj;
    float4 xv = *(const float4*)(xb + off);
    uint2 ov = *(const uint2*)&R1[c * 68 + t0];
    float4 r;
    r.x = xv.x + bf2f((u16)(ov.x & 0xFFFFu));
    r.y = xv.y + bf2f((u16)(ov.x >> 16));
    r.z = xv.z + bf2f((u16)(ov.y & 0xFFFFu));
    r.w = xv.w + bf2f((u16)(ov.y >> 16));
    *(float4*)(ob + off) = r;
  }
}

// ---------------- launcher ----------------
extern "C" void kernel_launch(void* const* d_in, const int* in_sizes, int n_in,
                              void* d_out, int out_size, void* d_ws, size_t ws_size,
                              hipStream_t stream) {
  const float* x      = (const float*)d_in[0];
  const float* qkv_w  = (const float*)d_in[2];
  const float* q_bias = (const float*)d_in[3];
  const float* v_bias = (const float*)d_in[4];
  const float* ls     = (const float*)d_in[5];
  const float* w1     = (const float*)d_in[6];
  const float* b1     = (const float*)d_in[7];
  const float* w2     = (const float*)d_in[8];
  const float* proj_w = (const float*)d_in[9];
  const float* proj_b = (const float*)d_in[10];

  u16*   wq    = (u16*)d_ws;                               // 110592 bf16
  u16*   wpv   = wq + 110592;                              // 36864 bf16 -> byte 294912
  float* qkvb  = (float*)((char*)d_ws + 294912);           // 576 f32   -> 297216
  float* bias3 = (float*)((char*)d_ws + 297216);           // 32768 f32 -> 428288
  float* table = (float*)((char*)d_ws + 428288);           // 1800 f32
  float* out   = (float*)d_out;

  hipLaunchKernelGGL(k_convert, dim3(579), dim3(256), 0, stream,
                     qkv_w, proj_w, q_bias, v_bias, wq, wpv, qkvb);
  hipLaunchKernelGGL(k_table, dim3(225), dim3(256), 0, stream, w1, b1, w2, table);
  hipLaunchKernelGGL(k_biasfill, dim3(128), dim3(256), 0, stream, table, bias3);
  hipLaunchKernelGGL(k_main, dim3(NWIN), dim3(512), 0, stream,
                     x, ls, proj_b, wq, wpv, qkvb, bias3, out);
}